// Round 2
// baseline (503.972 us; speedup 1.0000x reference)
//
#include <hip/hip_runtime.h>
#include <hip/hip_bf16.h>

#define BB 32
#define TT 16
#define NNODE 512
#define CC 128

typedef __attribute__((ext_vector_type(8))) short bf16x8;
typedef __attribute__((ext_vector_type(4))) short short4_t;
typedef __attribute__((ext_vector_type(4))) float f32x4;

__device__ __forceinline__ short f2bf(float f) {
    __hip_bfloat16 h = __float2bfloat16(f);
    return *reinterpret_cast<short*>(&h);
}

#define GLD16(g, l)                                                          \
    __builtin_amdgcn_global_load_lds(                                        \
        (const __attribute__((address_space(1))) unsigned int*)(g),          \
        (__attribute__((address_space(3))) unsigned int*)(l), 16, 0, 0)

// ---------------------------------------------------------------------------
// Row-normalize prep, 1 or 2 layers per pass (row sum computed once).
// Abf[b][n][m] = bf16( (adj[n,m] + lamm1*delta_nm) / (sum_m adj[n,m] + lamm1) )
// ---------------------------------------------------------------------------
__global__ void prep_adj_kernel(const float* __restrict__ adj,
                                const float* __restrict__ lambdas, int layer0,
                                short* __restrict__ Abf0,
                                short* __restrict__ Abf1) {
    int gid = blockIdx.x * blockDim.x + threadIdx.x;
    int row = gid >> 6;  // 0..16383 (b*512+n)
    int lane = gid & 63;
    int n = row & (NNODE - 1);
    const float* r = adj + (long)row * NNODE;
    float4 f0 = *(const float4*)(r + lane * 4);
    float4 f1 = *(const float4*)(r + 256 + lane * 4);
    float s = f0.x + f0.y + f0.z + f0.w + f1.x + f1.y + f1.z + f1.w;
#pragma unroll
    for (int o = 32; o; o >>= 1) s += __shfl_xor(s, o, 64);
    float base[8] = {f0.x, f0.y, f0.z, f0.w, f1.x, f1.y, f1.z, f1.w};
    int d0 = n - lane * 4;
    int d1 = n - 256 - lane * 4;
#pragma unroll
    for (int l = 0; l < 2; ++l) {
        short* dst = l ? Abf1 : Abf0;
        if (dst == nullptr) continue;
        float lamm1 = fmaxf(lambdas[layer0 + l], 0.f);
        float inv = 1.f / (s + lamm1);
        float v[8];
#pragma unroll
        for (int j = 0; j < 8; ++j) v[j] = base[j] * inv;
        if (d0 >= 0 && d0 < 4) v[d0] += lamm1 * inv;
        if (d1 >= 0 && d1 < 4) v[4 + d1] += lamm1 * inv;
        short* o = dst + (long)row * NNODE;
        short4_t s0 = {f2bf(v[0]), f2bf(v[1]), f2bf(v[2]), f2bf(v[3])};
        short4_t s1 = {f2bf(v[4]), f2bf(v[5]), f2bf(v[6]), f2bf(v[7])};
        *(short4_t*)(o + lane * 4) = s0;
        *(short4_t*)(o + 256 + lane * 4) = s1;
    }
}

// thT[l][i][k] = bf16(theta[l][k][i]) for both layers in one dispatch
__global__ void prep_theta_kernel(const float* __restrict__ thetas,
                                  short* __restrict__ thT) {
    int idx = blockIdx.x * 256 + threadIdx.x;  // 0..32767
    int l = idx >> 14;
    int r = idx & 16383;
    int i = r >> 7, k = r & (CC - 1);
    thT[l * CC * CC + i * CC + k] = f2bf(thetas[l * CC * CC + k * CC + i]);
}

// ---------------------------------------------------------------------------
// theta GEMM (layer 0): D[m][c] = X[m][k] @ theta[k][c], stored TRANSPOSED
// as Ht[bt][c][m_local] (bf16). theta resident in padded LDS (loaded once);
// X streamed directly global->reg (fp32->bf16) -- no A-LDS, no K-loop
// barriers, compiler pipelines all loads.
// ---------------------------------------------------------------------------
__global__ __launch_bounds__(256) void gemm_theta_mfma(
    const float* __restrict__ X, const short* __restrict__ thT,
    short* __restrict__ Ht) {
    __shared__ short Bs[128][136];  // [c_out][k], +8 pad (2-way banks = free)
    const int t = threadIdx.x;
    const long rowBase = (long)blockIdx.x * 128;
    const int w = t >> 6, ln = t & 63;
    const int lm = ln & 15, q = ln >> 4;
    const int wy = w >> 1, wx = w & 1;

    {   // cooperative one-time B load: 2 threads per row, coalesced
        int row = t >> 1, half = (t & 1) * 64;
        const short* src = thT + row * CC + half;
#pragma unroll
        for (int j = 0; j < 8; ++j)
            *(bf16x8*)(&Bs[row][half + j * 8]) = *(const bf16x8*)(src + j * 8);
    }
    __syncthreads();

    f32x4 acc[4][4] = {};
    const float* Xr = X + (rowBase + wy * 64 + lm) * CC;
#pragma unroll
    for (int k0 = 0; k0 < CC; k0 += 32) {
        bf16x8 a[4], b[4];
#pragma unroll
        for (int i = 0; i < 4; ++i) {
            const float* p = Xr + i * 16 * CC + k0 + q * 8;
            float4 g0 = *(const float4*)(p);
            float4 g1 = *(const float4*)(p + 4);
            bf16x8 av;
            av[0] = f2bf(g0.x); av[1] = f2bf(g0.y);
            av[2] = f2bf(g0.z); av[3] = f2bf(g0.w);
            av[4] = f2bf(g1.x); av[5] = f2bf(g1.y);
            av[6] = f2bf(g1.z); av[7] = f2bf(g1.w);
            a[i] = av;
        }
#pragma unroll
        for (int j = 0; j < 4; ++j)
            b[j] = *(const bf16x8*)(&Bs[wx * 64 + j * 16 + lm][k0 + q * 8]);
#pragma unroll
        for (int i = 0; i < 4; ++i)
#pragma unroll
            for (int j = 0; j < 4; ++j)
                acc[i][j] = __builtin_amdgcn_mfma_f32_16x16x32_bf16(
                    a[i], b[j], acc[i][j], 0, 0, 0);
    }

    const long bt = rowBase >> 9;
    const int mBase = (int)(rowBase & (NNODE - 1));
    short* Hb = Ht + bt * (long)(NNODE * CC);
#pragma unroll
    for (int i = 0; i < 4; ++i) {
        int m = mBase + wy * 64 + i * 16 + q * 4;
#pragma unroll
        for (int j = 0; j < 4; ++j) {
            int c = wx * 64 + j * 16 + lm;
            f32x4 v = acc[i][j];
            short4_t sv = {f2bf(v[0]), f2bf(v[1]), f2bf(v[2]), f2bf(v[3])};
            *(short4_t*)(&Hb[(long)c * NNODE + m]) = sv;
        }
    }
}

// ---------------------------------------------------------------------------
// FUSED agg(layer0) + theta(layer1), 2-phase double-buffered staging:
// next K-chunk's global_load_lds issued BEFORE current chunk's MFMA, so HBM
// latency hides under compute; __syncthreads' implicit vmcnt drain keeps it
// correct. XCD-chunked block swizzle for L2 locality (2048 = 8*256).
// ---------------------------------------------------------------------------
__global__ __launch_bounds__(256) void gemm_agg_theta(
    const short* __restrict__ Abf, const short* __restrict__ Ht1,
    const short* __restrict__ thT2, short* __restrict__ Ht2) {
    // phase1: As[2] @ 0/4096, Bs[2] @ 8192/12288 (dbuf);
    // phase2: Ts[128][136] overlays everything (34816 B total)
    __shared__ short sh[17408];
    const int t = threadIdx.x;
    const int bid = blockIdx.x;
    const int wid = (bid & 7) * 256 + (bid >> 3);  // XCD-chunked, bijective
    const int bt = wid >> 2;
    const int n0 = (wid & 3) * 128;
    const short* Ab = Abf + (long)(bt >> 4) * NNODE * NNODE + (long)n0 * NNODE;
    const short* Hb = Ht1 + (long)bt * NNODE * CC;
    const int w = t >> 6, ln = t & 63;
    const int lm = ln & 15, q = ln >> 4;
    const int wy = w >> 1, wx = w & 1;

    f32x4 acc[4][4] = {};

    const int rr = w * 32 + (ln >> 2);
    const int kc = (ln & 3) * 8;
    const short* ga = Ab + (long)rr * NNODE + kc;
    const short* gb = Hb + (long)rr * NNODE + kc;
    const int lofs = w * 1024 + ln * 8;

    GLD16(ga, sh + lofs);
    GLD16(ga + 16 * NNODE, sh + lofs + 512);
    GLD16(gb, sh + 8192 + lofs);
    GLD16(gb + 16 * NNODE, sh + 8192 + lofs + 512);
    __syncthreads();
    int sel = 0;
    for (int k0 = 0; k0 < NNODE; k0 += 32) {
        if (k0 + 32 < NNODE) {
            const int no = (sel ^ 1) * 4096 + lofs;
            GLD16(ga + k0 + 32, sh + no);
            GLD16(ga + k0 + 32 + 16 * NNODE, sh + no + 512);
            GLD16(gb + k0 + 32, sh + 8192 + no);
            GLD16(gb + k0 + 32 + 16 * NNODE, sh + 8192 + no + 512);
        }
        const short* Ac = sh + sel * 4096;
        const short* Bc = sh + 8192 + sel * 4096;
        bf16x8 a[4], b[4];
#pragma unroll
        for (int i = 0; i < 4; ++i)
            a[i] = *(const bf16x8*)(Ac + (wy * 64 + i * 16 + lm) * 32 + q * 8);
#pragma unroll
        for (int j = 0; j < 4; ++j)
            b[j] = *(const bf16x8*)(Bc + (wx * 64 + j * 16 + lm) * 32 + q * 8);
#pragma unroll
        for (int i = 0; i < 4; ++i)
#pragma unroll
            for (int j = 0; j < 4; ++j)
                acc[i][j] = __builtin_amdgcn_mfma_f32_16x16x32_bf16(
                    a[i], b[j], acc[i][j], 0, 0, 0);
        __syncthreads();
        sel ^= 1;
    }

    // relu + bf16-round tile into Ts[m_local][c] (same rounding point as the
    // unfused pipeline -> bit-identical)
    short(*Ts)[136] = (short(*)[136])sh;
#pragma unroll
    for (int i = 0; i < 4; ++i)
#pragma unroll
        for (int j = 0; j < 4; ++j)
#pragma unroll
            for (int r2 = 0; r2 < 4; ++r2)
                Ts[wy * 64 + i * 16 + q * 4 + r2][wx * 64 + j * 16 + lm] =
                    f2bf(fmaxf(acc[i][j][r2], 0.f));
    __syncthreads();

    // second GEMM (K = C = 128): A from Ts, B direct global->reg (thT2 is
    // 32 KB, L2-hot for every block) -- zero barriers, fully unrolled
    f32x4 acc2[4][4] = {};
#pragma unroll
    for (int c0 = 0; c0 < CC; c0 += 32) {
        bf16x8 a[4], b[4];
#pragma unroll
        for (int i = 0; i < 4; ++i)
            a[i] = *(const bf16x8*)(&Ts[wy * 64 + i * 16 + lm][c0 + q * 8]);
#pragma unroll
        for (int j = 0; j < 4; ++j)
            b[j] = *(const bf16x8*)(thT2 + (wx * 64 + j * 16 + lm) * CC + c0 +
                                    q * 8);
#pragma unroll
        for (int i = 0; i < 4; ++i)
#pragma unroll
            for (int j = 0; j < 4; ++j)
                acc2[i][j] = __builtin_amdgcn_mfma_f32_16x16x32_bf16(
                    a[i], b[j], acc2[i][j], 0, 0, 0);
    }

    short* Hb2 = Ht2 + (long)bt * NNODE * CC;
#pragma unroll
    for (int i = 0; i < 4; ++i) {
        int m = n0 + wy * 64 + i * 16 + q * 4;
#pragma unroll
        for (int j = 0; j < 4; ++j) {
            int c = wx * 64 + j * 16 + lm;
            f32x4 v = acc2[i][j];
            short4_t sv = {f2bf(v[0]), f2bf(v[1]), f2bf(v[2]), f2bf(v[3])};
            *(short4_t*)(&Hb2[(long)c * NNODE + m]) = sv;
        }
    }
}

// ---------------------------------------------------------------------------
// final agg GEMM: out = relu(x) + sigmoid(relu(Abf1 @ Ht2)); 2-phase dbuf
// staging + XCD swizzle, fused epilogue.
// ---------------------------------------------------------------------------
__global__ __launch_bounds__(256) void gemm_agg_mfma(
    const short* __restrict__ Abf, const short* __restrict__ Ht,
    const float* __restrict__ x, float* __restrict__ Out) {
    __shared__ short sh[16384];  // As[2] @ 0/4096, Bs[2] @ 8192/12288
    const int t = threadIdx.x;
    const int bid = blockIdx.x;
    const int wid = (bid & 7) * 256 + (bid >> 3);
    const int bt = wid >> 2;
    const int n0 = (wid & 3) * 128;
    const short* Ab = Abf + (long)(bt >> 4) * NNODE * NNODE + (long)n0 * NNODE;
    const short* Hb = Ht + (long)bt * NNODE * CC;
    const int w = t >> 6, ln = t & 63;
    const int lm = ln & 15, q = ln >> 4;
    const int wy = w >> 1, wx = w & 1;

    f32x4 acc[4][4] = {};

    const int rr = w * 32 + (ln >> 2);
    const int kc = (ln & 3) * 8;
    const short* ga = Ab + (long)rr * NNODE + kc;
    const short* gb = Hb + (long)rr * NNODE + kc;
    const int lofs = w * 1024 + ln * 8;

    GLD16(ga, sh + lofs);
    GLD16(ga + 16 * NNODE, sh + lofs + 512);
    GLD16(gb, sh + 8192 + lofs);
    GLD16(gb + 16 * NNODE, sh + 8192 + lofs + 512);
    __syncthreads();
    int sel = 0;
    for (int k0 = 0; k0 < NNODE; k0 += 32) {
        if (k0 + 32 < NNODE) {
            const int no = (sel ^ 1) * 4096 + lofs;
            GLD16(ga + k0 + 32, sh + no);
            GLD16(ga + k0 + 32 + 16 * NNODE, sh + no + 512);
            GLD16(gb + k0 + 32, sh + 8192 + no);
            GLD16(gb + k0 + 32 + 16 * NNODE, sh + 8192 + no + 512);
        }
        const short* Ac = sh + sel * 4096;
        const short* Bc = sh + 8192 + sel * 4096;
        bf16x8 a[4], b[4];
#pragma unroll
        for (int i = 0; i < 4; ++i)
            a[i] = *(const bf16x8*)(Ac + (wy * 64 + i * 16 + lm) * 32 + q * 8);
#pragma unroll
        for (int j = 0; j < 4; ++j)
            b[j] = *(const bf16x8*)(Bc + (wx * 64 + j * 16 + lm) * 32 + q * 8);
#pragma unroll
        for (int i = 0; i < 4; ++i)
#pragma unroll
            for (int j = 0; j < 4; ++j)
                acc[i][j] = __builtin_amdgcn_mfma_f32_16x16x32_bf16(
                    a[i], b[j], acc[i][j], 0, 0, 0);
        __syncthreads();
        sel ^= 1;
    }

    const long obase = (long)bt * NNODE * CC;
#pragma unroll
    for (int i = 0; i < 4; ++i) {
        int n = n0 + wy * 64 + i * 16 + q * 4;
#pragma unroll
        for (int j = 0; j < 4; ++j) {
            int c = wx * 64 + j * 16 + lm;
#pragma unroll
            for (int r2 = 0; r2 < 4; ++r2) {
                long idx = obase + (long)(n + r2) * CC + c;
                float v = fmaxf(acc[i][j][r2], 0.f);
                Out[idx] = fmaxf(x[idx], 0.f) + 1.f / (1.f + __expf(-v));
            }
        }
    }
}

extern "C" void kernel_launch(void* const* d_in, const int* in_sizes, int n_in,
                              void* d_out, int out_size, void* d_ws,
                              size_t ws_size, hipStream_t stream) {
    const float* x = (const float*)d_in[0];
    const float* adj = (const float*)d_in[1];
    const float* lambdas = (const float*)d_in[2];
    const float* thetas = (const float*)d_in[3];
    float* out = (float*)d_out;

    const long abf_elems = (long)BB * NNODE * NNODE;    // 8.39M shorts
    const long ht_elems = (long)BB * TT * NNODE * CC;   // 33.6M shorts
    // two-Abf layout needs ~100.7 MB; fall back to Abf reuse otherwise
    const bool two =
        ws_size >= (size_t)(2 * abf_elems + ht_elems + 2 * CC * CC) * 2;

    short* Abf0 = (short*)d_ws;
    short* Abf1 = two ? Abf0 + abf_elems : Abf0;
    short* Ht2 = Abf1 + abf_elems;
    short* thT0 = Ht2 + ht_elems;
    short* thT1 = thT0 + CC * CC;
    // Ht1 (67.1 MB bf16) lives in the out buffer (134 MB fp32): dead before
    // the final agg GEMM overwrites this memory with fp32 output.
    short* Ht1 = (short*)out;

    dim3 blk(256);

    if (two) {
        prep_adj_kernel<<<4096, blk, 0, stream>>>(adj, lambdas, 0, Abf0, Abf1);
        prep_theta_kernel<<<128, blk, 0, stream>>>(thetas, thT0);
        gemm_theta_mfma<<<2048, blk, 0, stream>>>(x, thT0, Ht1);
        gemm_agg_theta<<<2048, blk, 0, stream>>>(Abf0, Ht1, thT1, Ht2);
        gemm_agg_mfma<<<2048, blk, 0, stream>>>(Abf1, Ht2, x, out);
    } else {
        prep_adj_kernel<<<4096, blk, 0, stream>>>(adj, lambdas, 0, Abf0,
                                                  nullptr);
        prep_theta_kernel<<<128, blk, 0, stream>>>(thetas, thT0);
        gemm_theta_mfma<<<2048, blk, 0, stream>>>(x, thT0, Ht1);
        gemm_agg_theta<<<2048, blk, 0, stream>>>(Abf0, Ht1, thT1, Ht2);
        prep_adj_kernel<<<4096, blk, 0, stream>>>(adj, lambdas, 1, Abf0,
                                                  nullptr);
        gemm_agg_mfma<<<2048, blk, 0, stream>>>(Abf0, Ht2, x, out);
    }
}

// Round 4
// 445.090 us; speedup vs baseline: 1.1323x; 1.1323x over previous
//
#include <hip/hip_runtime.h>
#include <hip/hip_bf16.h>

#define BB 32
#define TT 16
#define NNODE 512
#define CC 128

typedef __attribute__((ext_vector_type(8))) short bf16x8;
typedef __attribute__((ext_vector_type(4))) short short4_t;
typedef __attribute__((ext_vector_type(4))) float f32x4;

__device__ __forceinline__ short f2bf(float f) {
    __hip_bfloat16 h = __float2bfloat16(f);
    return *reinterpret_cast<short*>(&h);
}

#define GLD16(g, l)                                                          \
    __builtin_amdgcn_global_load_lds(                                        \
        (const __attribute__((address_space(1))) unsigned int*)(g),          \
        (__attribute__((address_space(3))) unsigned int*)(l), 16, 0, 0)

// ---------------------------------------------------------------------------
// Row-normalize prep, writes both layers' Abf in one pass over adj.
// Abf[b][n][m] = bf16( (adj[n,m] + lamm1*delta_nm) / (sum_m adj[n,m] + lamm1) )
// ---------------------------------------------------------------------------
__global__ void prep_adj_kernel(const float* __restrict__ adj,
                                const float* __restrict__ lambdas, int layer0,
                                short* __restrict__ Abf0,
                                short* __restrict__ Abf1) {
    int gid = blockIdx.x * blockDim.x + threadIdx.x;
    int row = gid >> 6;  // 0..16383 (b*512+n)
    int lane = gid & 63;
    int n = row & (NNODE - 1);
    const float* r = adj + (long)row * NNODE;
    float4 f0 = *(const float4*)(r + lane * 4);
    float4 f1 = *(const float4*)(r + 256 + lane * 4);
    float s = f0.x + f0.y + f0.z + f0.w + f1.x + f1.y + f1.z + f1.w;
#pragma unroll
    for (int o = 32; o; o >>= 1) s += __shfl_xor(s, o, 64);
    float base[8] = {f0.x, f0.y, f0.z, f0.w, f1.x, f1.y, f1.z, f1.w};
    int d0 = n - lane * 4;
    int d1 = n - 256 - lane * 4;
#pragma unroll
    for (int l = 0; l < 2; ++l) {
        short* dst = l ? Abf1 : Abf0;
        if (dst == nullptr) continue;
        float lamm1 = fmaxf(lambdas[layer0 + l], 0.f);
        float inv = 1.f / (s + lamm1);
        float v[8];
#pragma unroll
        for (int j = 0; j < 8; ++j) v[j] = base[j] * inv;
        if (d0 >= 0 && d0 < 4) v[d0] += lamm1 * inv;
        if (d1 >= 0 && d1 < 4) v[4 + d1] += lamm1 * inv;
        short* o = dst + (long)row * NNODE;
        short4_t s0 = {f2bf(v[0]), f2bf(v[1]), f2bf(v[2]), f2bf(v[3])};
        short4_t s1 = {f2bf(v[4]), f2bf(v[5]), f2bf(v[6]), f2bf(v[7])};
        *(short4_t*)(o + lane * 4) = s0;
        *(short4_t*)(o + 256 + lane * 4) = s1;
    }
}

// thT[l][i][k] = bf16(theta[l][k][i]) for both layers in one dispatch
__global__ void prep_theta_kernel(const float* __restrict__ thetas,
                                  short* __restrict__ thT) {
    int idx = blockIdx.x * 256 + threadIdx.x;  // 0..32767
    int l = idx >> 14;
    int r = idx & 16383;
    int i = r >> 7, k = r & (CC - 1);
    thT[l * CC * CC + i * CC + k] = f2bf(thetas[l * CC * CC + k * CC + i]);
}

// ---------------------------------------------------------------------------
// theta GEMM (layer 0): D[m][c] = X[m][k] @ theta[k][c], stored TRANSPOSED
// as Ht[bt][c][m_local] (bf16). theta resident in padded LDS (loaded once);
// X streamed directly global->reg (fp32->bf16) -- no A-LDS, no K-loop
// barriers, compiler pipelines all loads.
// ---------------------------------------------------------------------------
__global__ __launch_bounds__(256) void gemm_theta_mfma(
    const float* __restrict__ X, const short* __restrict__ thT,
    short* __restrict__ Ht) {
    __shared__ short Bs[128][136];  // [c_out][k], +8 pad (2-way banks = free)
    const int t = threadIdx.x;
    const long rowBase = (long)blockIdx.x * 128;
    const int w = t >> 6, ln = t & 63;
    const int lm = ln & 15, q = ln >> 4;
    const int wy = w >> 1, wx = w & 1;

    {   // cooperative one-time B load: 2 threads per row, coalesced
        int row = t >> 1, half = (t & 1) * 64;
        const short* src = thT + row * CC + half;
#pragma unroll
        for (int j = 0; j < 8; ++j)
            *(bf16x8*)(&Bs[row][half + j * 8]) = *(const bf16x8*)(src + j * 8);
    }
    __syncthreads();

    f32x4 acc[4][4] = {};
    const float* Xr = X + (rowBase + wy * 64 + lm) * CC;
#pragma unroll
    for (int k0 = 0; k0 < CC; k0 += 32) {
        bf16x8 a[4], b[4];
#pragma unroll
        for (int i = 0; i < 4; ++i) {
            const float* p = Xr + i * 16 * CC + k0 + q * 8;
            float4 g0 = *(const float4*)(p);
            float4 g1 = *(const float4*)(p + 4);
            bf16x8 av;
            av[0] = f2bf(g0.x); av[1] = f2bf(g0.y);
            av[2] = f2bf(g0.z); av[3] = f2bf(g0.w);
            av[4] = f2bf(g1.x); av[5] = f2bf(g1.y);
            av[6] = f2bf(g1.z); av[7] = f2bf(g1.w);
            a[i] = av;
        }
#pragma unroll
        for (int j = 0; j < 4; ++j)
            b[j] = *(const bf16x8*)(&Bs[wx * 64 + j * 16 + lm][k0 + q * 8]);
#pragma unroll
        for (int i = 0; i < 4; ++i)
#pragma unroll
            for (int j = 0; j < 4; ++j)
                acc[i][j] = __builtin_amdgcn_mfma_f32_16x16x32_bf16(
                    a[i], b[j], acc[i][j], 0, 0, 0);
    }

    const long bt = rowBase >> 9;
    const int mBase = (int)(rowBase & (NNODE - 1));
    short* Hb = Ht + bt * (long)(NNODE * CC);
#pragma unroll
    for (int i = 0; i < 4; ++i) {
        int m = mBase + wy * 64 + i * 16 + q * 4;
#pragma unroll
        for (int j = 0; j < 4; ++j) {
            int c = wx * 64 + j * 16 + lm;
            f32x4 v = acc[i][j];
            short4_t sv = {f2bf(v[0]), f2bf(v[1]), f2bf(v[2]), f2bf(v[3])};
            *(short4_t*)(&Hb[(long)c * NNODE + m]) = sv;
        }
    }
}

// ---------------------------------------------------------------------------
// FUSED agg(layer0) + theta(layer1)  [round-1 proven structure: 2 barriers
// per K-chunk, no dbuf, no swizzle -- implicit wave-level overlap]:
//   tile = relu( Abf0[b][n0:n0+128][:] @ Ht1[bt][:][:] )   (K = 512)
//   Ht2[bt][cout][n0:n0+128] = tile[m][:] . thT2[cout][:]  (K = C = 128)
// ---------------------------------------------------------------------------
__global__ __launch_bounds__(256) void gemm_agg_theta(
    const short* __restrict__ Abf, const short* __restrict__ Ht1,
    const short* __restrict__ thT2, short* __restrict__ Ht2) {
    __shared__ short As[128 * 32];   // [n_local][k=m]
    __shared__ short Bs[128 * 32];   // [c][k=m]  (reused for thT2 tiles)
    __shared__ short Ts[128][136];   // relu'd tile [m_local][c], +8 pad
    const int t = threadIdx.x;
    const int bt = blockIdx.y;
    const int n0 = blockIdx.x * 128;
    const short* Ab = Abf + (long)(bt >> 4) * NNODE * NNODE + (long)n0 * NNODE;
    const short* Hb = Ht1 + (long)bt * NNODE * CC;
    const int w = t >> 6, ln = t & 63;
    const int lm = ln & 15, q = ln >> 4;
    const int wy = w >> 1, wx = w & 1;

    f32x4 acc[4][4] = {};

    const int rr = w * 32 + (ln >> 2);
    const int kc = (ln & 3) * 8;
    short* ldsA = As + w * 1024 + ln * 8;
    short* ldsB = Bs + w * 1024 + ln * 8;

    for (int k0 = 0; k0 < NNODE; k0 += 32) {
        __syncthreads();
        const short* ga = Ab + (long)rr * NNODE + k0 + kc;
        const short* gb = Hb + (long)rr * NNODE + k0 + kc;
        GLD16(ga, ldsA);
        GLD16(ga + 16 * NNODE, ldsA + 512);
        GLD16(gb, ldsB);
        GLD16(gb + 16 * NNODE, ldsB + 512);
        __syncthreads();

        bf16x8 a[4], b[4];
#pragma unroll
        for (int i = 0; i < 4; ++i)
            a[i] = *(const bf16x8*)(&As[(wy * 64 + i * 16 + lm) * 32 + q * 8]);
#pragma unroll
        for (int j = 0; j < 4; ++j)
            b[j] = *(const bf16x8*)(&Bs[(wx * 64 + j * 16 + lm) * 32 + q * 8]);
#pragma unroll
        for (int i = 0; i < 4; ++i)
#pragma unroll
            for (int j = 0; j < 4; ++j)
                acc[i][j] = __builtin_amdgcn_mfma_f32_16x16x32_bf16(
                    a[i], b[j], acc[i][j], 0, 0, 0);
    }

    // relu + bf16-round the tile into Ts[m_local][c] (same rounding point as
    // the unfused pipeline -> bit-identical)
#pragma unroll
    for (int i = 0; i < 4; ++i)
#pragma unroll
        for (int j = 0; j < 4; ++j)
#pragma unroll
            for (int r2 = 0; r2 < 4; ++r2)
                Ts[wy * 64 + i * 16 + q * 4 + r2][wx * 64 + j * 16 + lm] =
                    f2bf(fmaxf(acc[i][j][r2], 0.f));

    // second GEMM: K = C = 128, 4 steps; thT2 tiles staged into Bs via GLD16
    f32x4 acc2[4][4] = {};
    for (int c0 = 0; c0 < CC; c0 += 32) {
        __syncthreads();  // also covers Ts-writes -> Ts-reads (first iter)
        const short* gb = thT2 + rr * CC + c0 + kc;
        GLD16(gb, ldsB);
        GLD16(gb + 16 * CC, ldsB + 512);
        __syncthreads();

        bf16x8 a[4], b[4];
#pragma unroll
        for (int i = 0; i < 4; ++i)
            a[i] = *(const bf16x8*)(&Ts[wy * 64 + i * 16 + lm][c0 + q * 8]);
#pragma unroll
        for (int j = 0; j < 4; ++j)
            b[j] = *(const bf16x8*)(&Bs[(wx * 64 + j * 16 + lm) * 32 + q * 8]);
#pragma unroll
        for (int i = 0; i < 4; ++i)
#pragma unroll
            for (int j = 0; j < 4; ++j)
                acc2[i][j] = __builtin_amdgcn_mfma_f32_16x16x32_bf16(
                    a[i], b[j], acc2[i][j], 0, 0, 0);
    }

    // store transposed: Ht2[bt][cout][m], lane's 4 regs are consecutive m
    short* Hb2 = Ht2 + (long)bt * NNODE * CC;
#pragma unroll
    for (int i = 0; i < 4; ++i) {
        int m = n0 + wy * 64 + i * 16 + q * 4;
#pragma unroll
        for (int j = 0; j < 4; ++j) {
            int c = wx * 64 + j * 16 + lm;
            f32x4 v = acc2[i][j];
            short4_t sv = {f2bf(v[0]), f2bf(v[1]), f2bf(v[2]), f2bf(v[3])};
            *(short4_t*)(&Hb2[(long)c * NNODE + m]) = sv;
        }
    }
}

// ---------------------------------------------------------------------------
// final agg GEMM [round-1 proven structure]:
//   out[bt][n][c] = relu(x) + sigmoid(relu(Abf1 @ Ht2)), K = 512
// ---------------------------------------------------------------------------
__global__ __launch_bounds__(256) void gemm_agg_mfma(
    const short* __restrict__ Abf, const short* __restrict__ Ht,
    const float* __restrict__ x, float* __restrict__ Out) {
    __shared__ short As[128 * 32];  // [n_local][k=m]
    __shared__ short Bs[128 * 32];  // [c][k=m]
    const int t = threadIdx.x;
    const int bt = blockIdx.y;
    const int n0 = blockIdx.x * 128;
    const short* Ab = Abf + (long)(bt >> 4) * NNODE * NNODE + (long)n0 * NNODE;
    const short* Hb = Ht + (long)bt * NNODE * CC;
    const int w = t >> 6, ln = t & 63;
    const int lm = ln & 15, q = ln >> 4;
    const int wy = w >> 1, wx = w & 1;

    f32x4 acc[4][4] = {};

    const int rr = w * 32 + (ln >> 2);
    const int kc = (ln & 3) * 8;
    short* ldsA = As + w * 1024 + ln * 8;
    short* ldsB = Bs + w * 1024 + ln * 8;

    for (int k0 = 0; k0 < NNODE; k0 += 32) {
        __syncthreads();
        const short* ga = Ab + (long)rr * NNODE + k0 + kc;
        const short* gb = Hb + (long)rr * NNODE + k0 + kc;
        GLD16(ga, ldsA);
        GLD16(ga + 16 * NNODE, ldsA + 512);
        GLD16(gb, ldsB);
        GLD16(gb + 16 * NNODE, ldsB + 512);
        __syncthreads();

        bf16x8 a[4], b[4];
#pragma unroll
        for (int i = 0; i < 4; ++i)
            a[i] = *(const bf16x8*)(&As[(wy * 64 + i * 16 + lm) * 32 + q * 8]);
#pragma unroll
        for (int j = 0; j < 4; ++j)
            b[j] = *(const bf16x8*)(&Bs[(wx * 64 + j * 16 + lm) * 32 + q * 8]);
#pragma unroll
        for (int i = 0; i < 4; ++i)
#pragma unroll
            for (int j = 0; j < 4; ++j)
                acc[i][j] = __builtin_amdgcn_mfma_f32_16x16x32_bf16(
                    a[i], b[j], acc[i][j], 0, 0, 0);
    }

    const long obase = (long)bt * NNODE * CC;
#pragma unroll
    for (int i = 0; i < 4; ++i) {
        int n = n0 + wy * 64 + i * 16 + q * 4;
#pragma unroll
        for (int j = 0; j < 4; ++j) {
            int c = wx * 64 + j * 16 + lm;
#pragma unroll
            for (int r2 = 0; r2 < 4; ++r2) {
                long idx = obase + (long)(n + r2) * CC + c;
                float v = fmaxf(acc[i][j][r2], 0.f);
                Out[idx] = fmaxf(x[idx], 0.f) + 1.f / (1.f + __expf(-v));
            }
        }
    }
}

extern "C" void kernel_launch(void* const* d_in, const int* in_sizes, int n_in,
                              void* d_out, int out_size, void* d_ws,
                              size_t ws_size, hipStream_t stream) {
    const float* x = (const float*)d_in[0];
    const float* adj = (const float*)d_in[1];
    const float* lambdas = (const float*)d_in[2];
    const float* thetas = (const float*)d_in[3];
    float* out = (float*)d_out;

    const long abf_elems = (long)BB * NNODE * NNODE;    // 8.39M shorts
    const long ht_elems = (long)BB * TT * NNODE * CC;   // 33.6M shorts
    // two-Abf layout needs ~100.7 MB; fall back to Abf reuse otherwise
    const bool two =
        ws_size >= (size_t)(2 * abf_elems + ht_elems + 2 * CC * CC) * 2;

    short* Abf0 = (short*)d_ws;
    short* Abf1 = two ? Abf0 + abf_elems : Abf0;
    short* Ht2 = Abf1 + abf_elems;
    short* thT0 = Ht2 + ht_elems;
    short* thT1 = thT0 + CC * CC;
    // Ht1 (67.1 MB bf16) lives in the out buffer (134 MB fp32): dead before
    // the final agg GEMM overwrites this memory with fp32 output.
    short* Ht1 = (short*)out;

    dim3 blk(256);
    dim3 g_agg(NNODE / 128, BB * TT);

    if (two) {
        prep_adj_kernel<<<4096, blk, 0, stream>>>(adj, lambdas, 0, Abf0, Abf1);
        prep_theta_kernel<<<128, blk, 0, stream>>>(thetas, thT0);
        gemm_theta_mfma<<<2048, blk, 0, stream>>>(x, thT0, Ht1);
        gemm_agg_theta<<<g_agg, blk, 0, stream>>>(Abf0, Ht1, thT1, Ht2);
        gemm_agg_mfma<<<g_agg, blk, 0, stream>>>(Abf1, Ht2, x, out);
    } else {
        prep_adj_kernel<<<4096, blk, 0, stream>>>(adj, lambdas, 0, Abf0,
                                                  nullptr);
        prep_theta_kernel<<<128, blk, 0, stream>>>(thetas, thT0);
        gemm_theta_mfma<<<2048, blk, 0, stream>>>(x, thT0, Ht1);
        gemm_agg_theta<<<g_agg, blk, 0, stream>>>(Abf0, Ht1, thT1, Ht2);
        prep_adj_kernel<<<4096, blk, 0, stream>>>(adj, lambdas, 1, Abf0,
                                                  nullptr);
        gemm_agg_mfma<<<g_agg, blk, 0, stream>>>(Abf0, Ht2, x, out);
    }
}